// Round 1
// baseline (550.912 us; speedup 1.0000x reference)
//
#include <hip/hip_runtime.h>

#define NROWS 500000
#define DD 128
#define NSTACK 12
#define BNEPS 1e-3f

typedef float v2f __attribute__((ext_vector_type(2)));
typedef float v4f __attribute__((ext_vector_type(4)));

// One thread per row.
// Phase 1: stream x once, accumulate its projection onto all 50 output
//          columns (12 layers x 4 units + 2 final-logit columns).
// Phase 2: sequential 12-layer recurrence using only the y-history part
//          (widths 0,4,...,44 -> 1056 MACs) + BN + ReLU.
// Phase 3: final logits (48 y-terms) + softmax(2).
__global__ __launch_bounds__(256) void predict_kernel(
    const float* __restrict__ x,
    const float* __restrict__ w0,  const float* __restrict__ w1,
    const float* __restrict__ w2,  const float* __restrict__ w3,
    const float* __restrict__ w4,  const float* __restrict__ w5,
    const float* __restrict__ w6,  const float* __restrict__ w7,
    const float* __restrict__ w8,  const float* __restrict__ w9,
    const float* __restrict__ w10, const float* __restrict__ w11,
    const float* __restrict__ gamma_, const float* __restrict__ beta_,
    const float* __restrict__ mean_,  const float* __restrict__ var_,
    const float* __restrict__ wf,     const float* __restrict__ bf,
    float* __restrict__ out)
{
    const int row = blockIdx.x * blockDim.x + threadIdx.x;
    if (row >= NROWS) return;

    const float* ws[NSTACK] = {w0,w1,w2,w3,w4,w5,w6,w7,w8,w9,w10,w11};

    // T[2i], T[2i+1] = x-projection for layer i units (0,1),(2,3); T[24] = final logits x-part
    v2f T[25];
#pragma unroll
    for (int j = 0; j < 25; ++j) T[j] = (v2f){0.0f, 0.0f};

    const v4f* __restrict__ xv = (const v4f*)(x + (size_t)row * DD);

    for (int kk = 0; kk < DD / 4; ++kk) {   // dynamic uniform loop counter
        const v4f xc = xv[kk];
#pragma unroll
        for (int c = 0; c < 4; ++c) {
            const float xk = xc[c];
            const int k = kk * 4 + c;
#pragma unroll
            for (int i = 0; i < NSTACK; ++i) {
                // layer i: x occupies rows [4i, 4i+128) of w_i; row-major [rows,4]
                const v4f wr = *(const v4f*)(ws[i] + (size_t)((4 * i + k) * 4));
                const v2f wlo = {wr.x, wr.y};
                const v2f whi = {wr.z, wr.w};
                T[2 * i]     += xk * wlo;
                T[2 * i + 1] += xk * whi;
            }
            // final dense: x occupies rows [48, 176) of wf; row-major [176,2]
            const v2f wfr = *(const v2f*)(wf + (size_t)((48 + k) * 2));
            T[24] += xk * wfr;
        }
    }

    // Sequential recurrence: h_i = [y_{i-1}, ..., y_0, x]
    float y[NSTACK * 4];
#pragma unroll
    for (int i = 0; i < NSTACK; ++i) {
        float acc[4];
#pragma unroll
        for (int u = 0; u < 4; ++u) acc[u] = T[2 * i + (u >> 1)][u & 1];
        // history part: w_i row m (m<4i) multiplies y_{i-1-(m>>2)}[m&3]
#pragma unroll
        for (int j = 0; j < i; ++j) {
#pragma unroll
            for (int u2 = 0; u2 < 4; ++u2) {
                const float hv = y[(i - 1 - j) * 4 + u2];
                const v4f wr = *(const v4f*)(ws[i] + (size_t)((4 * j + u2) * 4));
                acc[0] += hv * wr.x;
                acc[1] += hv * wr.y;
                acc[2] += hv * wr.z;
                acc[3] += hv * wr.w;
            }
        }
#pragma unroll
        for (int u = 0; u < 4; ++u) {
            const float g  = gamma_[i * 4 + u];
            const float bt = beta_[i * 4 + u];
            const float mn = mean_[i * 4 + u];
            const float vr = var_[i * 4 + u];
            const float sc = g * __frsqrt_rn(vr + BNEPS);
            const float sh = bt - mn * sc;
            const float v  = acc[u] * sc + sh;
            y[i * 4 + u] = v > 0.0f ? v : 0.0f;
        }
    }

    // Final logits: h_12 = [y_11, ..., y_0, x]; rows [0,48) of wf are y-history
    float l0 = T[24].x + bf[0];
    float l1 = T[24].y + bf[1];
#pragma unroll
    for (int m = 0; m < 48; ++m) {
        const float hv = y[(11 - (m >> 2)) * 4 + (m & 3)];
        l0 += hv * wf[m * 2 + 0];
        l1 += hv * wf[m * 2 + 1];
    }

    const float mx = fmaxf(l0, l1);
    const float e0 = __expf(l0 - mx);
    const float e1 = __expf(l1 - mx);
    const float inv = 1.0f / (e0 + e1);
    const v2f res = {e0 * inv, e1 * inv};
    *(v2f*)(out + (size_t)row * 2) = res;
}

extern "C" void kernel_launch(void* const* d_in, const int* in_sizes, int n_in,
                              void* d_out, int out_size, void* d_ws, size_t ws_size,
                              hipStream_t stream) {
    const float* x   = (const float*)d_in[0];
    const float* w0  = (const float*)d_in[1];
    const float* w1  = (const float*)d_in[2];
    const float* w2  = (const float*)d_in[3];
    const float* w3  = (const float*)d_in[4];
    const float* w4  = (const float*)d_in[5];
    const float* w5  = (const float*)d_in[6];
    const float* w6  = (const float*)d_in[7];
    const float* w7  = (const float*)d_in[8];
    const float* w8  = (const float*)d_in[9];
    const float* w9  = (const float*)d_in[10];
    const float* w10 = (const float*)d_in[11];
    const float* w11 = (const float*)d_in[12];
    const float* gm  = (const float*)d_in[13];
    const float* bt  = (const float*)d_in[14];
    const float* mn  = (const float*)d_in[15];
    const float* vr  = (const float*)d_in[16];
    const float* wf  = (const float*)d_in[17];
    const float* bf  = (const float*)d_in[18];
    float* out = (float*)d_out;

    dim3 block(256);
    dim3 grid((NROWS + 255) / 256);
    hipLaunchKernelGGL(predict_kernel, grid, block, 0, stream,
                       x, w0, w1, w2, w3, w4, w5, w6, w7, w8, w9, w10, w11,
                       gm, bt, mn, vr, wf, bf, out);
}

// Round 2
// 458.430 us; speedup vs baseline: 1.2017x; 1.2017x over previous
//
#include <hip/hip_runtime.h>

#define NROWS 500000
#define DD 128
#define NSTACK 12
#define BNEPS 1e-3f
#define NCOL 50           // 48 layer-unit columns + 2 final-logit columns
#define WXSTRIDE 52       // pad 50 -> 52 floats: 208B, divisible by 16 (b128-aligned rows)

typedef float v2f __attribute__((ext_vector_type(2)));
typedef float v4f __attribute__((ext_vector_type(4)));

// One thread per row; all weights staged in LDS (broadcast ds_read in hot loop).
// Phase 1: stream x once, accumulate projection onto all 50 columns.
// Phase 2: sequential 12-layer recurrence (history part only) + BN + ReLU.
// Phase 3: final logits + softmax(2).
__global__ __launch_bounds__(256) void predict_kernel(
    const float* __restrict__ x,
    const float* __restrict__ w0,  const float* __restrict__ w1,
    const float* __restrict__ w2,  const float* __restrict__ w3,
    const float* __restrict__ w4,  const float* __restrict__ w5,
    const float* __restrict__ w6,  const float* __restrict__ w7,
    const float* __restrict__ w8,  const float* __restrict__ w9,
    const float* __restrict__ w10, const float* __restrict__ w11,
    const float* __restrict__ gamma_, const float* __restrict__ beta_,
    const float* __restrict__ mean_,  const float* __restrict__ var_,
    const float* __restrict__ wf,     const float* __restrict__ bf,
    float* __restrict__ out)
{
    // ---- LDS staging ----
    __shared__ __align__(16) float WX[DD * WXSTRIDE]; // [k][col] transposed x-weights
    __shared__ __align__(16) float WH[1056];          // history weights, per-layer packed
    __shared__ __align__(16) float WFY[96];           // wf rows 0..47 (y-history part)
    __shared__ float SC[48];                          // BN scale
    __shared__ float SH[48];                          // BN shift
    __shared__ float BF[2];

    const int tid = threadIdx.x;
    const float* ws[NSTACK] = {w0,w1,w2,w3,w4,w5,w6,w7,w8,w9,w10,w11};

    // WX[k*52 + c]: c<48 -> ws[c>>2][16*(c>>2) + 4*k + (c&3)] ; c in {48,49} -> wf[96 + 2k + c-48]
    for (int idx = tid; idx < DD * NCOL; idx += 256) {
        const int k = idx / NCOL;
        const int c = idx - k * NCOL;
        float v;
        if (c < 48) {
            const int i = c >> 2, u = c & 3;
            v = ws[i][16 * i + 4 * k + u];
        } else {
            v = wf[96 + 2 * k + (c - 48)];
        }
        WX[k * WXSTRIDE + c] = v;
    }
    // History weights: layer i rows [0,4i) are the first 16i floats of ws[i]; offset 8i(i-1)
#pragma unroll
    for (int i = 1; i < NSTACK; ++i) {
        const int off = 8 * i * (i - 1);
        for (int idx = tid; idx < 16 * i; idx += 256) WH[off + idx] = ws[i][idx];
    }
    for (int idx = tid; idx < 96; idx += 256) WFY[idx] = wf[idx];
    if (tid < 48) {
        const float sc = gamma_[tid] / sqrtf(var_[tid] + BNEPS);
        SC[tid] = sc;
        SH[tid] = beta_[tid] - mean_[tid] * sc;
    }
    if (tid < 2) BF[tid] = bf[tid];
    __syncthreads();

    const int row = blockIdx.x * blockDim.x + tid;
    if (row >= NROWS) return;

    // ---- Phase 1: x projection onto 50 columns ----
    v2f T[25];
#pragma unroll
    for (int j = 0; j < 25; ++j) T[j] = (v2f){0.0f, 0.0f};

    const v4f* __restrict__ xv = (const v4f*)(x + (size_t)row * DD);

#pragma unroll 2
    for (int kk = 0; kk < DD / 4; ++kk) {
        const v4f xc = xv[kk];
#pragma unroll
        for (int c = 0; c < 4; ++c) {
            const float xk = xc[c];
            const float* wrow = &WX[(kk * 4 + c) * WXSTRIDE];
#pragma unroll
            for (int j = 0; j < NSTACK; ++j) {
                const v4f w = *(const v4f*)(wrow + 4 * j);   // broadcast ds_read_b128
                T[2 * j]     += xk * (v2f){w.x, w.y};
                T[2 * j + 1] += xk * (v2f){w.z, w.w};
            }
            const v2f w2 = *(const v2f*)(wrow + 48);
            T[24] += xk * w2;
        }
    }

    // ---- Phase 2: sequential recurrence ----
    float y[NSTACK * 4];
#pragma unroll
    for (int i = 0; i < NSTACK; ++i) {
        float acc0 = T[2 * i].x, acc1 = T[2 * i].y;
        float acc2 = T[2 * i + 1].x, acc3 = T[2 * i + 1].y;
        const float* wh = &WH[8 * i * (i - 1)];
#pragma unroll
        for (int m = 0; m < 4 * i; ++m) {
            const float hv = y[(i - 1 - (m >> 2)) * 4 + (m & 3)];
            const v4f wv = *(const v4f*)(wh + 4 * m);        // broadcast ds_read_b128
            acc0 += hv * wv.x; acc1 += hv * wv.y;
            acc2 += hv * wv.z; acc3 += hv * wv.w;
        }
        const float* sc = &SC[4 * i];
        const float* sh = &SH[4 * i];
        float r0 = acc0 * sc[0] + sh[0];
        float r1 = acc1 * sc[1] + sh[1];
        float r2 = acc2 * sc[2] + sh[2];
        float r3 = acc3 * sc[3] + sh[3];
        y[i * 4 + 0] = r0 > 0.0f ? r0 : 0.0f;
        y[i * 4 + 1] = r1 > 0.0f ? r1 : 0.0f;
        y[i * 4 + 2] = r2 > 0.0f ? r2 : 0.0f;
        y[i * 4 + 3] = r3 > 0.0f ? r3 : 0.0f;
    }

    // ---- Phase 3: final logits + softmax ----
    float l0 = T[24].x + BF[0];
    float l1 = T[24].y + BF[1];
#pragma unroll
    for (int m = 0; m < 48; ++m) {
        const float hv = y[(11 - (m >> 2)) * 4 + (m & 3)];
        const v2f wv = *(const v2f*)(&WFY[2 * m]);
        l0 += hv * wv.x;
        l1 += hv * wv.y;
    }

    const float mx = fmaxf(l0, l1);
    const float e0 = __expf(l0 - mx);
    const float e1 = __expf(l1 - mx);
    const float inv = 1.0f / (e0 + e1);
    *(v2f*)(out + (size_t)row * 2) = (v2f){e0 * inv, e1 * inv};
}

extern "C" void kernel_launch(void* const* d_in, const int* in_sizes, int n_in,
                              void* d_out, int out_size, void* d_ws, size_t ws_size,
                              hipStream_t stream) {
    const float* x   = (const float*)d_in[0];
    const float* w0  = (const float*)d_in[1];
    const float* w1  = (const float*)d_in[2];
    const float* w2  = (const float*)d_in[3];
    const float* w3  = (const float*)d_in[4];
    const float* w4  = (const float*)d_in[5];
    const float* w5  = (const float*)d_in[6];
    const float* w6  = (const float*)d_in[7];
    const float* w7  = (const float*)d_in[8];
    const float* w8  = (const float*)d_in[9];
    const float* w9  = (const float*)d_in[10];
    const float* w10 = (const float*)d_in[11];
    const float* w11 = (const float*)d_in[12];
    const float* gm  = (const float*)d_in[13];
    const float* bt  = (const float*)d_in[14];
    const float* mn  = (const float*)d_in[15];
    const float* vr  = (const float*)d_in[16];
    const float* wf  = (const float*)d_in[17];
    const float* bf  = (const float*)d_in[18];
    float* out = (float*)d_out;

    dim3 block(256);
    dim3 grid((NROWS + 255) / 256);
    hipLaunchKernelGGL(predict_kernel, grid, block, 0, stream,
                       x, w0, w1, w2, w3, w4, w5, w6, w7, w8, w9, w10, w11,
                       gm, bt, mn, vr, wf, bf, out);
}